// Round 8
// baseline (505.636 us; speedup 1.0000x reference)
//
#include <hip/hip_runtime.h>
#include <math.h>

#define EMB 1024
#define TSEQ 2048
#define NBATCH 4
#define NHEAD 16
#define HDIM 64
#define MROWS (NBATCH * TSEQ) /* 8192 */
#define KPAD 72

typedef __attribute__((ext_vector_type(8))) short bf16x8;
typedef __attribute__((ext_vector_type(4))) float f32x4;
typedef __attribute__((ext_vector_type(8))) unsigned short u16x8;
typedef __attribute__((ext_vector_type(4))) unsigned short u16x4;

typedef __attribute__((address_space(1))) const void gas_cv;
typedef __attribute__((address_space(3))) void las_v;

__device__ __forceinline__ void gload_lds16(const void* g, void* l) {
  __builtin_amdgcn_global_load_lds((gas_cv*)g, (las_v*)l, 16, 0, 0);
}

__device__ __forceinline__ unsigned short f2bf(float f) {
  unsigned int x = __float_as_uint(f);
  unsigned int r = x + 0x7fffu + ((x >> 16) & 1u);
  return (unsigned short)(r >> 16);
}
__device__ __forceinline__ float bf2f(unsigned short h) {
  return __uint_as_float((unsigned int)h << 16);
}

// ---------------------------------------------------------------------------
// Decompose fp32 tensors into bf16 hi/lo pairs. 12M elems total, 8 per thread.
// ---------------------------------------------------------------------------
__global__ __launch_bounds__(256) void decomp_kernel(
    const float* __restrict__ x, const float* __restrict__ Wk,
    const float* __restrict__ Wq, const float* __restrict__ Wv,
    const float* __restrict__ Wu,
    unsigned short* __restrict__ xh, unsigned short* __restrict__ xl,
    unsigned short* __restrict__ wkh, unsigned short* __restrict__ wkl,
    unsigned short* __restrict__ wqh, unsigned short* __restrict__ wql,
    unsigned short* __restrict__ wvh, unsigned short* __restrict__ wvl,
    unsigned short* __restrict__ wuh, unsigned short* __restrict__ wul) {
  const int v = blockIdx.x * blockDim.x + threadIdx.x;  // vec8 id
  const float* src;
  unsigned short *dh, *dl;
  size_t off;
  if (v < (1 << 20)) {
    src = x; dh = xh; dl = xl; off = (size_t)v << 3;
  } else {
    const int wv = v - (1 << 20);
    const int ws_ = wv >> 17;
    off = (size_t)(wv & 131071) << 3;
    if (ws_ == 0) { src = Wk; dh = wkh; dl = wkl; }
    else if (ws_ == 1) { src = Wq; dh = wqh; dl = wql; }
    else if (ws_ == 2) { src = Wv; dh = wvh; dl = wvl; }
    else { src = Wu; dh = wuh; dl = wul; }
  }
  const float4 f0 = *(const float4*)(src + off);
  const float4 f1 = *(const float4*)(src + off + 4);
  const float fv[8] = {f0.x, f0.y, f0.z, f0.w, f1.x, f1.y, f1.z, f1.w};
  u16x8 h, l;
#pragma unroll
  for (int i = 0; i < 8; ++i) {
    const unsigned short hb = f2bf(fv[i]);
    h[i] = hb;
    l[i] = f2bf(fv[i] - bf2f(hb));
  }
  *(u16x8*)(dh + off) = h;
  *(u16x8*)(dl + off) = l;
}

// ---------------------------------------------------------------------------
// Split-bf16 3-pass MFMA GEMM core (unchanged, proven): hi*hi + hi*lo + lo*hi.
// ---------------------------------------------------------------------------
__device__ __forceinline__ void gemm3_core(
    const unsigned short* __restrict__ Ah, const unsigned short* __restrict__ Al,
    const unsigned short* __restrict__ Bh, const unsigned short* __restrict__ Bl,
    int bm, int bn, f32x4 acc[4][4]) {
  __shared__ __align__(16) unsigned short As[128][64];
  __shared__ __align__(16) unsigned short Bs[128][64];
  const int tid = threadIdx.x;
  const int lane = tid & 63;
  const int w = tid >> 6;
  const int lq = lane & 15;
  const int g = lane >> 4;
  const int wrO = (w >> 1) << 6;
  const int wcO = (w & 1) << 6;
  const int srow = (w << 5) + (lane >> 3);
  const int scbs = ((lane & 7) ^ (srow & 7)) << 3;  // pre-swizzled src col (elems)
  const int xsw = lq & 7;                           // read-side swizzle

  const size_t aoff0 = (size_t)(bm + srow) * EMB + scbs;
  const size_t boff0 = (size_t)(bn + srow) * EMB + scbs;

  for (int s = 0; s < 48; ++s) {
    const int p = s >> 4;
    const int kt = s & 15;
    const unsigned short* Asrc = (p < 2) ? Ah : Al;
    const unsigned short* Bsrc = (p == 1) ? Bl : Bh;
    const size_t ko = (size_t)(kt << 6);
    __syncthreads();  // previous compute done before overwrite
#pragma unroll
    for (int u = 0; u < 4; ++u) {
      gload_lds16(Asrc + aoff0 + ko + (size_t)(u << 3) * EMB,
                  &As[(w << 5) + (u << 3)][0]);
      gload_lds16(Bsrc + boff0 + ko + (size_t)(u << 3) * EMB,
                  &Bs[(w << 5) + (u << 3)][0]);
    }
    __syncthreads();  // vmcnt drained by compiler before barrier

    bf16x8 af[4][2], bf[4][2];
#pragma unroll
    for (int m = 0; m < 4; ++m)
#pragma unroll
      for (int kk = 0; kk < 2; ++kk) {
        af[m][kk] = *(const bf16x8*)&As[wrO + (m << 4) + lq]
                                      [(((kk << 2) + g) ^ xsw) << 3];
        bf[m][kk] = *(const bf16x8*)&Bs[wcO + (m << 4) + lq]
                                      [(((kk << 2) + g) ^ xsw) << 3];
      }
#pragma unroll
    for (int kk = 0; kk < 2; ++kk)
#pragma unroll
      for (int m = 0; m < 4; ++m)
#pragma unroll
        for (int nb = 0; nb < 4; ++nb)
          acc[m][nb] = __builtin_amdgcn_mfma_f32_16x16x32_bf16(
              af[m][kk], bf[nb][kk], acc[m][nb], 0, 0, 0);
  }
}

// ---------------------------------------------------------------------------
// QKV projections with fused per-head LayerNorm (k,q -> bf16) and transposed
// bf16 v. Grid (64, 24): blockIdx.y>>3 selects k/q/v.
// ---------------------------------------------------------------------------
__global__ __launch_bounds__(256, 2) void gemm3_qkv_kernel(
    const unsigned short* __restrict__ xh, const unsigned short* __restrict__ xl,
    const unsigned short* __restrict__ wkh, const unsigned short* __restrict__ wkl,
    const unsigned short* __restrict__ wqh, const unsigned short* __restrict__ wql,
    const unsigned short* __restrict__ wvh, const unsigned short* __restrict__ wvl,
    unsigned short* __restrict__ kb16, unsigned short* __restrict__ qb16,
    unsigned short* __restrict__ vb16,
    const float* __restrict__ klnw, const float* __restrict__ klnb,
    const float* __restrict__ qlnw, const float* __restrict__ qlnb) {
  const int sel = blockIdx.y >> 3;
  const int bm = blockIdx.x << 7;
  const int bn = (blockIdx.y & 7) << 7;
  const unsigned short* Bh = sel == 0 ? wkh : sel == 1 ? wqh : wvh;
  const unsigned short* Bl = sel == 0 ? wkl : sel == 1 ? wql : wvl;

  f32x4 acc[4][4];
#pragma unroll
  for (int m = 0; m < 4; ++m)
#pragma unroll
    for (int nb = 0; nb < 4; ++nb) acc[m][nb] = (f32x4){0.f, 0.f, 0.f, 0.f};

  gemm3_core(xh, xl, Bh, Bl, bm, bn, acc);

  const int lane = threadIdx.x & 63;
  const int w = threadIdx.x >> 6;
  const int lq = lane & 15;
  const int g = lane >> 4;
  const int wrO = (w >> 1) << 6;
  const int wcO = (w & 1) << 6;

  if (sel < 2) {
    // fused per-head LayerNorm: each wave's 64-col span is exactly one head
    unsigned short* C = sel == 0 ? kb16 : qb16;
    const float* lw = sel == 0 ? klnw : qlnw;
    const float* lb = sel == 0 ? klnb : qlnb;
    float wd[4], bd[4];
#pragma unroll
    for (int nb = 0; nb < 4; ++nb) {
      wd[nb] = lw[(nb << 4) + lq];
      bd[nb] = lb[(nb << 4) + lq];
    }
#pragma unroll
    for (int m = 0; m < 4; ++m) {
      const int r0 = bm + wrO + (m << 4) + (g << 2);
#pragma unroll
      for (int j = 0; j < 4; ++j) {
        float s = acc[m][0][j] + acc[m][1][j] + acc[m][2][j] + acc[m][3][j];
        s += __shfl_xor(s, 1, 64); s += __shfl_xor(s, 2, 64);
        s += __shfl_xor(s, 4, 64); s += __shfl_xor(s, 8, 64);
        const float mu = s * (1.f / 64.f);
        float v2 = 0.f;
#pragma unroll
        for (int nb = 0; nb < 4; ++nb) {
          const float d = acc[m][nb][j] - mu;
          v2 = fmaf(d, d, v2);
        }
        v2 += __shfl_xor(v2, 1, 64); v2 += __shfl_xor(v2, 2, 64);
        v2 += __shfl_xor(v2, 4, 64); v2 += __shfl_xor(v2, 8, 64);
        const float inv = rsqrtf(v2 * (1.f / 64.f) + 1e-5f);
#pragma unroll
        for (int nb = 0; nb < 4; ++nb) {
          const float val = (acc[m][nb][j] - mu) * inv * wd[nb] + bd[nb];
          C[(size_t)(r0 + j) * EMB + bn + wcO + (nb << 4) + lq] = f2bf(val);
        }
      }
    }
  } else {
    // v: bf16, transposed per head: vb16[((b*16+h)*64+d)*2048 + t]
#pragma unroll
    for (int m = 0; m < 4; ++m) {
      const int r0 = bm + wrO + (m << 4) + (g << 2);
      const int bb = r0 >> 11;
      const int tl = r0 & 2047;
#pragma unroll
      for (int nb = 0; nb < 4; ++nb) {
        const int n = bn + wcO + (nb << 4) + lq;
        const int hh = n >> 6;
        const int dd = n & 63;
        u16x4 pk;
#pragma unroll
        for (int j = 0; j < 4; ++j) pk[j] = f2bf(acc[m][nb][j]);
        *(u16x4*)(vb16 + ((((size_t)(bb << 4) + hh) << 6) + dd) * TSEQ + tl) = pk;
      }
    }
  }
}

// ---------------------------------------------------------------------------
// Output projection: A = attention out (hi/lo bf16), B = Wu (hi/lo), C fp32.
// ---------------------------------------------------------------------------
__global__ __launch_bounds__(256, 2) void gemm3_out_kernel(
    const unsigned short* __restrict__ ah, const unsigned short* __restrict__ al,
    const unsigned short* __restrict__ wuh, const unsigned short* __restrict__ wul,
    float* __restrict__ C) {
  const int bm = blockIdx.x << 7;
  const int bn = blockIdx.y << 7;
  f32x4 acc[4][4];
#pragma unroll
  for (int m = 0; m < 4; ++m)
#pragma unroll
    for (int nb = 0; nb < 4; ++nb) acc[m][nb] = (f32x4){0.f, 0.f, 0.f, 0.f};

  gemm3_core(ah, al, wuh, wul, bm, bn, acc);

  const int lane = threadIdx.x & 63;
  const int w = threadIdx.x >> 6;
  const int lq = lane & 15;
  const int g = lane >> 4;
  const int wrO = (w >> 1) << 6;
  const int wcO = (w & 1) << 6;
#pragma unroll
  for (int m = 0; m < 4; ++m) {
    const int r0 = bm + wrO + (m << 4) + (g << 2);
#pragma unroll
    for (int nb = 0; nb < 4; ++nb) {
      const int c = bn + wcO + (nb << 4) + lq;
#pragma unroll
      for (int j = 0; j < 4; ++j) C[(size_t)(r0 + j) * EMB + c] = acc[m][nb][j];
    }
  }
}

// ---------------------------------------------------------------------------
// bf16-MFMA causal flash attention, v2:
//  - LDS double-buffered K/V, ONE barrier per tile
//  - async-STAGE (T14): next tile's global loads issued before compute,
//    ds_writes after PV
//  - exp2 rebase (exact: scale folded as 0.125*log2e)
//  - defer-max THR=0 (exact: skip O-rescale when tile max <= running max)
//  - setprio around MFMA clusters (T5)
// ---------------------------------------------------------------------------
#define SCL2E 0.1803368801111244f /* 0.125 * log2(e) */

__global__ __launch_bounds__(256, 3) void attn_kernel(
    const unsigned short* __restrict__ Qg, const unsigned short* __restrict__ Kg,
    const unsigned short* __restrict__ Vt,
    unsigned short* __restrict__ Oh, unsigned short* __restrict__ Ol) {
  __shared__ __align__(16) unsigned short Ks[2][64][KPAD];
  __shared__ __align__(16) unsigned short Vs[2][64][KPAD];
  __shared__ __align__(16) unsigned short Ps[4][16][KPAD];
  const int tid = threadIdx.x;
  const int lane = tid & 63;
  const int w = tid >> 6;
  const int lq = lane & 15;
  const int g = lane >> 4;
  const int qt = (int)(gridDim.x - 1 - blockIdx.x);  // big blocks first
  const int bh = blockIdx.y;
  const int bb = bh >> 4;
  const int hh = bh & 15;
  const int q0 = qt << 6;
  const unsigned short* Qb = Qg + ((size_t)bb * TSEQ) * EMB + hh * HDIM;
  const unsigned short* Kb = Kg + ((size_t)bb * TSEQ) * EMB + hh * HDIM;
  const unsigned short* Vb = Vt + (size_t)bh * HDIM * TSEQ;
  unsigned short* Ohb = Oh + ((size_t)bb * TSEQ) * EMB + hh * HDIM;
  unsigned short* Olb = Ol + ((size_t)bb * TSEQ) * EMB + hh * HDIM;

  bf16x8 qf0, qf1;
  {
    const unsigned short* qp = Qb + (size_t)(q0 + (w << 4) + lq) * EMB + (g << 3);
    qf0 = *(const bf16x8*)(qp);
    qf1 = *(const bf16x8*)(qp + 32);
  }

  f32x4 o[4];
#pragma unroll
  for (int nb = 0; nb < 4; ++nb) o[nb] = (f32x4){0.f, 0.f, 0.f, 0.f};
  float mrun = -3.0e38f;
  float lrun = 0.f;
  const int qg_row = q0 + (w << 4) + lq;

  const int skey = tid >> 2;            // staging row 0..63
  const int schunk = (tid & 3) << 4;    // staging col base (16 elems)
  const unsigned short* kp_base = Kb + (size_t)skey * EMB + schunk;
  const unsigned short* vp_base = Vb + (size_t)skey * TSEQ + schunk;

  bf16x8 kr0, kr1, vr0, vr1;
  // prologue: stage tile 0 into buffer 0
  kr0 = *(const bf16x8*)kp_base;
  kr1 = *(const bf16x8*)(kp_base + 8);
  vr0 = *(const bf16x8*)vp_base;
  vr1 = *(const bf16x8*)(vp_base + 8);
  *(bf16x8*)&Ks[0][skey][schunk] = kr0;
  *(bf16x8*)&Ks[0][skey][schunk + 8] = kr1;
  *(bf16x8*)&Vs[0][skey][schunk] = vr0;
  *(bf16x8*)&Vs[0][skey][schunk + 8] = vr1;
  __syncthreads();

  for (int t = 0; t <= qt; ++t) {
    const int cur = t & 1;
    const int k0 = t << 6;
    // T14: issue next tile's global loads before compute
    if (t < qt) {
      const size_t k0n = (size_t)(t + 1) << 6;
      const unsigned short* kp = kp_base + k0n * EMB;
      kr0 = *(const bf16x8*)kp;
      kr1 = *(const bf16x8*)(kp + 8);
      const unsigned short* vp = vp_base + k0n;
      vr0 = *(const bf16x8*)vp;
      vr1 = *(const bf16x8*)(vp + 8);
    }

    // S^T = K * Q^T : acc[mb] rows = key 16mb+4g+r, col = q lq
    f32x4 sacc[4];
#pragma unroll
    for (int mb = 0; mb < 4; ++mb) sacc[mb] = (f32x4){0.f, 0.f, 0.f, 0.f};
    __builtin_amdgcn_s_setprio(1);
#pragma unroll
    for (int mb = 0; mb < 4; ++mb) {
      const bf16x8 ka0 = *(const bf16x8*)&Ks[cur][(mb << 4) + lq][(g << 3)];
      const bf16x8 ka1 = *(const bf16x8*)&Ks[cur][(mb << 4) + lq][(g << 3) + 32];
      sacc[mb] = __builtin_amdgcn_mfma_f32_16x16x32_bf16(ka0, qf0, sacc[mb], 0, 0, 0);
      sacc[mb] = __builtin_amdgcn_mfma_f32_16x16x32_bf16(ka1, qf1, sacc[mb], 0, 0, 0);
    }
    __builtin_amdgcn_s_setprio(0);

    // online softmax in exp2 domain (per q = lq; lane holds 16 of 64 keys)
    const bool diag = (t == qt);
    float pv[16];
    float pm = -3.0e38f;
#pragma unroll
    for (int mb = 0; mb < 4; ++mb)
#pragma unroll
      for (int r = 0; r < 4; ++r) {
        float s = sacc[mb][r] * SCL2E;
        if (diag && (k0 + (mb << 4) + (g << 2) + r) > qg_row) s = -3.0e38f;
        pv[(mb << 2) + r] = s;
        pm = fmaxf(pm, s);
      }
    pm = fmaxf(pm, __shfl_xor(pm, 16, 64));
    pm = fmaxf(pm, __shfl_xor(pm, 32, 64));

    const bool skip = __all(pm <= mrun);  // T13 THR=0: rescale is identity
    const float mnew = skip ? mrun : fmaxf(mrun, pm);
    float ls = 0.f;
#pragma unroll
    for (int i = 0; i < 16; ++i) {
      const float p = exp2f(pv[i] - mnew);
      pv[i] = p;
      ls += p;
    }
    ls += __shfl_xor(ls, 16, 64);
    ls += __shfl_xor(ls, 32, 64);
    if (skip) {
      lrun += ls;
    } else {
      const float corr = exp2f(mrun - mnew);  // exp2(-inf)=0 on first tile
      mrun = mnew;
      lrun = lrun * corr + ls;
      float corr4[4];
#pragma unroll
      for (int r = 0; r < 4; ++r)
        corr4[r] = __shfl(corr, (lane & 48) | ((g << 2) + r), 64);
#pragma unroll
      for (int nb = 0; nb < 4; ++nb)
#pragma unroll
        for (int r = 0; r < 4; ++r) o[nb][r] *= corr4[r];
    }

    // pack P (bf16) into per-wave LDS: Ps[w][q=lq][key]
    {
      unsigned int* pw = (unsigned int*)&Ps[w][lq][0];
#pragma unroll
      for (int mb = 0; mb < 4; ++mb) {
        const unsigned int u0 =
            (unsigned int)f2bf(pv[(mb << 2) + 0]) | ((unsigned int)f2bf(pv[(mb << 2) + 1]) << 16);
        const unsigned int u1 =
            (unsigned int)f2bf(pv[(mb << 2) + 2]) | ((unsigned int)f2bf(pv[(mb << 2) + 3]) << 16);
        pw[(mb << 3) + (g << 1) + 0] = u0;
        pw[(mb << 3) + (g << 1) + 1] = u1;
      }
    }
    // wave-private: only need our own writes visible to our own reads
    asm volatile("s_waitcnt lgkmcnt(0)" ::: "memory");

    // O += P * V  (A = P[q][key], B = V[key][d] via transposed Vs rows)
    {
      const bf16x8 pa0 = *(const bf16x8*)&Ps[w][lq][(g << 3)];
      const bf16x8 pa1 = *(const bf16x8*)&Ps[w][lq][(g << 3) + 32];
      __builtin_amdgcn_s_setprio(1);
#pragma unroll
      for (int nb = 0; nb < 4; ++nb) {
        const bf16x8 v0 = *(const bf16x8*)&Vs[cur][(nb << 4) + lq][(g << 3)];
        const bf16x8 v1 = *(const bf16x8*)&Vs[cur][(nb << 4) + lq][(g << 3) + 32];
        o[nb] = __builtin_amdgcn_mfma_f32_16x16x32_bf16(pa0, v0, o[nb], 0, 0, 0);
        o[nb] = __builtin_amdgcn_mfma_f32_16x16x32_bf16(pa1, v1, o[nb], 0, 0, 0);
      }
      __builtin_amdgcn_s_setprio(0);
    }

    // T14: write next tile to the other buffer (last read 1 barrier ago)
    if (t < qt) {
      const int nxt = cur ^ 1;
      *(bf16x8*)&Ks[nxt][skey][schunk] = kr0;
      *(bf16x8*)&Ks[nxt][skey][schunk + 8] = kr1;
      *(bf16x8*)&Vs[nxt][skey][schunk] = vr0;
      *(bf16x8*)&Vs[nxt][skey][schunk + 8] = vr1;
    }
    __syncthreads();
  }

  // normalize + write hi/lo: o[nb][r] = O[q=4g+r][d=16nb+lq]
  float li[4];
#pragma unroll
  for (int r = 0; r < 4; ++r)
    li[r] = 1.f / __shfl(lrun, (lane & 48) | ((g << 2) + r), 64);
#pragma unroll
  for (int nb = 0; nb < 4; ++nb)
#pragma unroll
    for (int r = 0; r < 4; ++r) {
      const float val = o[nb][r] * li[r];
      const unsigned short hb = f2bf(val);
      const size_t idx =
          (size_t)(q0 + (w << 4) + (g << 2) + r) * EMB + (nb << 4) + lq;
      Ohb[idx] = hb;
      Olb[idx] = f2bf(val - bf2f(hb));
    }
}

// ---------------------------------------------------------------------------
extern "C" void kernel_launch(void* const* d_in, const int* in_sizes, int n_in,
                              void* d_out, int out_size, void* d_ws, size_t ws_size,
                              hipStream_t stream) {
  const float* x  = (const float*)d_in[0];
  const float* Wk = (const float*)d_in[1];
  const float* Wq = (const float*)d_in[2];
  const float* Wv = (const float*)d_in[3];
  const float* Wu = (const float*)d_in[4];
  const float* klnw = (const float*)d_in[5];
  const float* klnb = (const float*)d_in[6];
  const float* qlnw = (const float*)d_in[7];
  const float* qlnb = (const float*)d_in[8];
  float* out = (float*)d_out;

  char* wsb = (char*)d_ws;
  const size_t MB = 1024 * 1024;
  unsigned short* ah   = (unsigned short*)(wsb + 0 * MB);    // attn out hi (16MB)
  unsigned short* al   = (unsigned short*)(wsb + 16 * MB);   // attn out lo (16MB)
  unsigned short* kb16 = (unsigned short*)(wsb + 32 * MB);
  unsigned short* qb16 = (unsigned short*)(wsb + 48 * MB);
  unsigned short* xh   = (unsigned short*)(wsb + 64 * MB);
  unsigned short* xl   = (unsigned short*)(wsb + 80 * MB);
  unsigned short* vb16 = (unsigned short*)(wsb + 96 * MB);
  unsigned short* wkh  = (unsigned short*)(wsb + 112 * MB);
  unsigned short* wkl  = (unsigned short*)(wsb + 114 * MB);
  unsigned short* wqh  = (unsigned short*)(wsb + 116 * MB);
  unsigned short* wql  = (unsigned short*)(wsb + 118 * MB);
  unsigned short* wvh  = (unsigned short*)(wsb + 120 * MB);
  unsigned short* wvl  = (unsigned short*)(wsb + 122 * MB);
  unsigned short* wuh  = (unsigned short*)(wsb + 124 * MB);
  unsigned short* wul  = (unsigned short*)(wsb + 126 * MB);

  // 1) hi/lo decomposition of x and all weights
  decomp_kernel<<<6144, 256, 0, stream>>>(x, Wk, Wq, Wv, Wu, xh, xl, wkh, wkl,
                                          wqh, wql, wvh, wvl, wuh, wul);

  // 2) QKV projections (split-bf16 MFMA) + fused per-head LN; v -> bf16^T
  gemm3_qkv_kernel<<<dim3(MROWS / 128, 24), 256, 0, stream>>>(
      xh, xl, wkh, wkl, wqh, wql, wvh, wvl, kb16, qb16, vb16,
      klnw, klnb, qlnw, qlnb);

  // 3) bf16-MFMA causal flash attention -> hi/lo bf16
  attn_kernel<<<dim3(TSEQ / 64, NBATCH * NHEAD), 256, 0, stream>>>(
      qb16, kb16, vb16, ah, al);

  // 4) output projection (split-bf16 MFMA) -> fp32 out
  gemm3_out_kernel<<<dim3(MROWS / 128, EMB / 128), 256, 0, stream>>>(
      ah, al, wuh, wul, out);
}

// Round 9
// 400.952 us; speedup vs baseline: 1.2611x; 1.2611x over previous
//
#include <hip/hip_runtime.h>
#include <math.h>

#define EMB 1024
#define TSEQ 2048
#define NBATCH 4
#define NHEAD 16
#define HDIM 64
#define MROWS (NBATCH * TSEQ) /* 8192 */
#define KPAD 72

typedef __attribute__((ext_vector_type(8))) short bf16x8;
typedef __attribute__((ext_vector_type(4))) float f32x4;
typedef __attribute__((ext_vector_type(8))) unsigned short u16x8;
typedef __attribute__((ext_vector_type(4))) unsigned short u16x4;

typedef __attribute__((address_space(1))) const void gas_cv;
typedef __attribute__((address_space(3))) void las_v;

__device__ __forceinline__ void gload_lds16(const void* g, void* l) {
  __builtin_amdgcn_global_load_lds((gas_cv*)g, (las_v*)l, 16, 0, 0);
}

__device__ __forceinline__ unsigned short f2bf(float f) {
  unsigned int x = __float_as_uint(f);
  unsigned int r = x + 0x7fffu + ((x >> 16) & 1u);
  return (unsigned short)(r >> 16);
}
__device__ __forceinline__ float bf2f(unsigned short h) {
  return __uint_as_float((unsigned int)h << 16);
}

// ---------------------------------------------------------------------------
// Decompose fp32 tensors into bf16 hi/lo pairs. 12M elems total, 8 per thread.
// ---------------------------------------------------------------------------
__global__ __launch_bounds__(256) void decomp_kernel(
    const float* __restrict__ x, const float* __restrict__ Wk,
    const float* __restrict__ Wq, const float* __restrict__ Wv,
    const float* __restrict__ Wu,
    unsigned short* __restrict__ xh, unsigned short* __restrict__ xl,
    unsigned short* __restrict__ wkh, unsigned short* __restrict__ wkl,
    unsigned short* __restrict__ wqh, unsigned short* __restrict__ wql,
    unsigned short* __restrict__ wvh, unsigned short* __restrict__ wvl,
    unsigned short* __restrict__ wuh, unsigned short* __restrict__ wul) {
  const int v = blockIdx.x * blockDim.x + threadIdx.x;  // vec8 id
  const float* src;
  unsigned short *dh, *dl;
  size_t off;
  if (v < (1 << 20)) {
    src = x; dh = xh; dl = xl; off = (size_t)v << 3;
  } else {
    const int wv = v - (1 << 20);
    const int ws_ = wv >> 17;
    off = (size_t)(wv & 131071) << 3;
    if (ws_ == 0) { src = Wk; dh = wkh; dl = wkl; }
    else if (ws_ == 1) { src = Wq; dh = wqh; dl = wql; }
    else if (ws_ == 2) { src = Wv; dh = wvh; dl = wvl; }
    else { src = Wu; dh = wuh; dl = wul; }
  }
  const float4 f0 = *(const float4*)(src + off);
  const float4 f1 = *(const float4*)(src + off + 4);
  const float fv[8] = {f0.x, f0.y, f0.z, f0.w, f1.x, f1.y, f1.z, f1.w};
  u16x8 h, l;
#pragma unroll
  for (int i = 0; i < 8; ++i) {
    const unsigned short hb = f2bf(fv[i]);
    h[i] = hb;
    l[i] = f2bf(fv[i] - bf2f(hb));
  }
  *(u16x8*)(dh + off) = h;
  *(u16x8*)(dl + off) = l;
}

// ---------------------------------------------------------------------------
// Split-bf16 2-pass MFMA GEMM core: acc = A*B^T over K=1024 as hi*hi + hi*lo.
// (lo*hi dropped: ~2^-9 relative error, far below the attention bf16 error.)
// Tile 128x128, BK=64, 256 threads (4 waves 2x2). global_load_lds(16B) with
// both-sides XOR swizzle (linear LDS dest, pre-swizzled source, swizzled read).
// ---------------------------------------------------------------------------
__device__ __forceinline__ void gemm3_core(
    const unsigned short* __restrict__ Ah,
    const unsigned short* __restrict__ Bh, const unsigned short* __restrict__ Bl,
    int bm, int bn, f32x4 acc[4][4]) {
  __shared__ __align__(16) unsigned short As[128][64];
  __shared__ __align__(16) unsigned short Bs[128][64];
  const int tid = threadIdx.x;
  const int lane = tid & 63;
  const int w = tid >> 6;
  const int lq = lane & 15;
  const int g = lane >> 4;
  const int wrO = (w >> 1) << 6;
  const int wcO = (w & 1) << 6;
  const int srow = (w << 5) + (lane >> 3);
  const int scbs = ((lane & 7) ^ (srow & 7)) << 3;  // pre-swizzled src col (elems)
  const int xsw = lq & 7;                           // read-side swizzle

  const size_t aoff0 = (size_t)(bm + srow) * EMB + scbs;
  const size_t boff0 = (size_t)(bn + srow) * EMB + scbs;

  for (int s = 0; s < 32; ++s) {
    const int p = s >> 4;
    const int kt = s & 15;
    const unsigned short* Bsrc = (p == 0) ? Bh : Bl;
    const size_t ko = (size_t)(kt << 6);
    __syncthreads();  // previous compute done before overwrite
#pragma unroll
    for (int u = 0; u < 4; ++u) {
      gload_lds16(Ah + aoff0 + ko + (size_t)(u << 3) * EMB,
                  &As[(w << 5) + (u << 3)][0]);
      gload_lds16(Bsrc + boff0 + ko + (size_t)(u << 3) * EMB,
                  &Bs[(w << 5) + (u << 3)][0]);
    }
    __syncthreads();  // vmcnt drained by compiler before barrier

    bf16x8 af[4][2], bf[4][2];
#pragma unroll
    for (int m = 0; m < 4; ++m)
#pragma unroll
      for (int kk = 0; kk < 2; ++kk) {
        af[m][kk] = *(const bf16x8*)&As[wrO + (m << 4) + lq]
                                      [(((kk << 2) + g) ^ xsw) << 3];
        bf[m][kk] = *(const bf16x8*)&Bs[wcO + (m << 4) + lq]
                                      [(((kk << 2) + g) ^ xsw) << 3];
      }
#pragma unroll
    for (int kk = 0; kk < 2; ++kk)
#pragma unroll
      for (int m = 0; m < 4; ++m)
#pragma unroll
        for (int nb = 0; nb < 4; ++nb)
          acc[m][nb] = __builtin_amdgcn_mfma_f32_16x16x32_bf16(
              af[m][kk], bf[nb][kk], acc[m][nb], 0, 0, 0);
  }
}

// ---------------------------------------------------------------------------
// QKV projections with fused per-head LayerNorm (k,q -> bf16) and transposed
// bf16 v. Grid (64, 24): blockIdx.y>>3 selects k/q/v.
// ---------------------------------------------------------------------------
__global__ __launch_bounds__(256, 2) void gemm3_qkv_kernel(
    const unsigned short* __restrict__ xh,
    const unsigned short* __restrict__ wkh, const unsigned short* __restrict__ wkl,
    const unsigned short* __restrict__ wqh, const unsigned short* __restrict__ wql,
    const unsigned short* __restrict__ wvh, const unsigned short* __restrict__ wvl,
    unsigned short* __restrict__ kb16, unsigned short* __restrict__ qb16,
    unsigned short* __restrict__ vb16,
    const float* __restrict__ klnw, const float* __restrict__ klnb,
    const float* __restrict__ qlnw, const float* __restrict__ qlnb) {
  const int sel = blockIdx.y >> 3;
  const int bm = blockIdx.x << 7;
  const int bn = (blockIdx.y & 7) << 7;
  const unsigned short* Bh = sel == 0 ? wkh : sel == 1 ? wqh : wvh;
  const unsigned short* Bl = sel == 0 ? wkl : sel == 1 ? wql : wvl;

  f32x4 acc[4][4];
#pragma unroll
  for (int m = 0; m < 4; ++m)
#pragma unroll
    for (int nb = 0; nb < 4; ++nb) acc[m][nb] = (f32x4){0.f, 0.f, 0.f, 0.f};

  gemm3_core(xh, Bh, Bl, bm, bn, acc);

  const int lane = threadIdx.x & 63;
  const int w = threadIdx.x >> 6;
  const int lq = lane & 15;
  const int g = lane >> 4;
  const int wrO = (w >> 1) << 6;
  const int wcO = (w & 1) << 6;

  if (sel < 2) {
    // fused per-head LayerNorm: each wave's 64-col span is exactly one head
    unsigned short* C = sel == 0 ? kb16 : qb16;
    const float* lw = sel == 0 ? klnw : qlnw;
    const float* lb = sel == 0 ? klnb : qlnb;
    float wd[4], bd[4];
#pragma unroll
    for (int nb = 0; nb < 4; ++nb) {
      wd[nb] = lw[(nb << 4) + lq];
      bd[nb] = lb[(nb << 4) + lq];
    }
#pragma unroll
    for (int m = 0; m < 4; ++m) {
      const int r0 = bm + wrO + (m << 4) + (g << 2);
#pragma unroll
      for (int j = 0; j < 4; ++j) {
        float s = acc[m][0][j] + acc[m][1][j] + acc[m][2][j] + acc[m][3][j];
        s += __shfl_xor(s, 1, 64); s += __shfl_xor(s, 2, 64);
        s += __shfl_xor(s, 4, 64); s += __shfl_xor(s, 8, 64);
        const float mu = s * (1.f / 64.f);
        float v2 = 0.f;
#pragma unroll
        for (int nb = 0; nb < 4; ++nb) {
          const float d = acc[m][nb][j] - mu;
          v2 = fmaf(d, d, v2);
        }
        v2 += __shfl_xor(v2, 1, 64); v2 += __shfl_xor(v2, 2, 64);
        v2 += __shfl_xor(v2, 4, 64); v2 += __shfl_xor(v2, 8, 64);
        const float inv = rsqrtf(v2 * (1.f / 64.f) + 1e-5f);
#pragma unroll
        for (int nb = 0; nb < 4; ++nb) {
          const float val = (acc[m][nb][j] - mu) * inv * wd[nb] + bd[nb];
          C[(size_t)(r0 + j) * EMB + bn + wcO + (nb << 4) + lq] = f2bf(val);
        }
      }
    }
  } else {
    // v: bf16, transposed per head: vb16[((b*16+h)*64+d)*2048 + t]
#pragma unroll
    for (int m = 0; m < 4; ++m) {
      const int r0 = bm + wrO + (m << 4) + (g << 2);
      const int bb = r0 >> 11;
      const int tl = r0 & 2047;
#pragma unroll
      for (int nb = 0; nb < 4; ++nb) {
        const int n = bn + wcO + (nb << 4) + lq;
        const int hh = n >> 6;
        const int dd = n & 63;
        u16x4 pk;
#pragma unroll
        for (int j = 0; j < 4; ++j) pk[j] = f2bf(acc[m][nb][j]);
        *(u16x4*)(vb16 + ((((size_t)(bb << 4) + hh) << 6) + dd) * TSEQ + tl) = pk;
      }
    }
  }
}

// ---------------------------------------------------------------------------
// Output projection: A = attention out (hi bf16), B = Wu (hi/lo), C fp32.
// ---------------------------------------------------------------------------
__global__ __launch_bounds__(256, 2) void gemm3_out_kernel(
    const unsigned short* __restrict__ ah,
    const unsigned short* __restrict__ wuh, const unsigned short* __restrict__ wul,
    float* __restrict__ C) {
  const int bm = blockIdx.x << 7;
  const int bn = blockIdx.y << 7;
  f32x4 acc[4][4];
#pragma unroll
  for (int m = 0; m < 4; ++m)
#pragma unroll
    for (int nb = 0; nb < 4; ++nb) acc[m][nb] = (f32x4){0.f, 0.f, 0.f, 0.f};

  gemm3_core(ah, wuh, wul, bm, bn, acc);

  const int lane = threadIdx.x & 63;
  const int w = threadIdx.x >> 6;
  const int lq = lane & 15;
  const int g = lane >> 4;
  const int wrO = (w >> 1) << 6;
  const int wcO = (w & 1) << 6;
#pragma unroll
  for (int m = 0; m < 4; ++m) {
    const int r0 = bm + wrO + (m << 4) + (g << 2);
#pragma unroll
    for (int nb = 0; nb < 4; ++nb) {
      const int c = bn + wcO + (nb << 4) + lq;
#pragma unroll
      for (int j = 0; j < 4; ++j) C[(size_t)(r0 + j) * EMB + c] = acc[m][nb][j];
    }
  }
}

// ---------------------------------------------------------------------------
// bf16-MFMA causal flash attention, v3 = proven v1 structure (single-buffer
// K/V, 2 barriers/tile, 27.6 KB LDS -> max residency) + exact micro-opts:
// exp2 rebase, defer-max THR=0, setprio around MFMA clusters.
// ---------------------------------------------------------------------------
#define SCL2E 0.1803368801111244f /* 0.125 * log2(e) */

__global__ __launch_bounds__(256, 2) void attn_kernel(
    const unsigned short* __restrict__ Qg, const unsigned short* __restrict__ Kg,
    const unsigned short* __restrict__ Vt,
    unsigned short* __restrict__ Oh, unsigned short* __restrict__ Ol) {
  __shared__ __align__(16) unsigned short Ks[64][KPAD];
  __shared__ __align__(16) unsigned short Vs[64][KPAD];
  __shared__ __align__(16) unsigned short Ps[4][16][KPAD];
  const int tid = threadIdx.x;
  const int lane = tid & 63;
  const int w = tid >> 6;
  const int lq = lane & 15;
  const int g = lane >> 4;
  const int qt = (int)(gridDim.x - 1 - blockIdx.x);  // big blocks first
  const int bh = blockIdx.y;
  const int bb = bh >> 4;
  const int hh = bh & 15;
  const int q0 = qt << 6;
  const unsigned short* Qb = Qg + ((size_t)bb * TSEQ) * EMB + hh * HDIM;
  const unsigned short* Kb = Kg + ((size_t)bb * TSEQ) * EMB + hh * HDIM;
  const unsigned short* Vb = Vt + (size_t)bh * HDIM * TSEQ;
  unsigned short* Ohb = Oh + ((size_t)bb * TSEQ) * EMB + hh * HDIM;
  unsigned short* Olb = Ol + ((size_t)bb * TSEQ) * EMB + hh * HDIM;

  bf16x8 qf0, qf1;
  {
    const unsigned short* qp = Qb + (size_t)(q0 + (w << 4) + lq) * EMB + (g << 3);
    qf0 = *(const bf16x8*)(qp);
    qf1 = *(const bf16x8*)(qp + 32);
  }

  f32x4 o[4];
#pragma unroll
  for (int nb = 0; nb < 4; ++nb) o[nb] = (f32x4){0.f, 0.f, 0.f, 0.f};
  float mrun = -3.0e38f;
  float lrun = 0.f;
  const int qg_row = q0 + (w << 4) + lq;

  const int skey = tid >> 2;            // staging row 0..63
  const int schunk = (tid & 3) << 4;    // staging col base (16 elems)

  for (int t = 0; t <= qt; ++t) {
    const int k0 = t << 6;
    // stage K (rows=key, cols=d) and V (rows=d, cols=key; Vt pre-transposed)
    {
      const unsigned short* kp = Kb + (size_t)(k0 + skey) * EMB + schunk;
      *(bf16x8*)&Ks[skey][schunk] = *(const bf16x8*)kp;
      *(bf16x8*)&Ks[skey][schunk + 8] = *(const bf16x8*)(kp + 8);
      const unsigned short* vp = Vb + (size_t)skey * TSEQ + k0 + schunk;
      *(bf16x8*)&Vs[skey][schunk] = *(const bf16x8*)vp;
      *(bf16x8*)&Vs[skey][schunk + 8] = *(const bf16x8*)(vp + 8);
    }
    __syncthreads();

    // S^T = K * Q^T : acc[mb] rows = key 16mb+4g+r, col = q lq
    f32x4 sacc[4];
#pragma unroll
    for (int mb = 0; mb < 4; ++mb) sacc[mb] = (f32x4){0.f, 0.f, 0.f, 0.f};
    __builtin_amdgcn_s_setprio(1);
#pragma unroll
    for (int mb = 0; mb < 4; ++mb) {
      const bf16x8 ka0 = *(const bf16x8*)&Ks[(mb << 4) + lq][(g << 3)];
      const bf16x8 ka1 = *(const bf16x8*)&Ks[(mb << 4) + lq][(g << 3) + 32];
      sacc[mb] = __builtin_amdgcn_mfma_f32_16x16x32_bf16(ka0, qf0, sacc[mb], 0, 0, 0);
      sacc[mb] = __builtin_amdgcn_mfma_f32_16x16x32_bf16(ka1, qf1, sacc[mb], 0, 0, 0);
    }
    __builtin_amdgcn_s_setprio(0);

    // online softmax in exp2 domain (per q = lq; lane holds 16 of 64 keys)
    const bool diag = (t == qt);
    float pv[16];
    float pm = -3.0e38f;
#pragma unroll
    for (int mb = 0; mb < 4; ++mb)
#pragma unroll
      for (int r = 0; r < 4; ++r) {
        float s = sacc[mb][r] * SCL2E;
        if (diag && (k0 + (mb << 4) + (g << 2) + r) > qg_row) s = -3.0e38f;
        pv[(mb << 2) + r] = s;
        pm = fmaxf(pm, s);
      }
    pm = fmaxf(pm, __shfl_xor(pm, 16, 64));
    pm = fmaxf(pm, __shfl_xor(pm, 32, 64));

    const bool skip = __all(pm <= mrun);  // T13 THR=0: rescale is identity
    const float mnew = skip ? mrun : fmaxf(mrun, pm);
    float ls = 0.f;
#pragma unroll
    for (int i = 0; i < 16; ++i) {
      const float p = exp2f(pv[i] - mnew);
      pv[i] = p;
      ls += p;
    }
    ls += __shfl_xor(ls, 16, 64);
    ls += __shfl_xor(ls, 32, 64);
    if (skip) {
      lrun += ls;
    } else {
      const float corr = exp2f(mrun - mnew);  // exp2(-inf)=0 on first tile
      mrun = mnew;
      lrun = lrun * corr + ls;
      float corr4[4];
#pragma unroll
      for (int r = 0; r < 4; ++r)
        corr4[r] = __shfl(corr, (lane & 48) | ((g << 2) + r), 64);
#pragma unroll
      for (int nb = 0; nb < 4; ++nb)
#pragma unroll
        for (int r = 0; r < 4; ++r) o[nb][r] *= corr4[r];
    }

    // pack P (bf16) into per-wave LDS: Ps[w][q=lq][key]
    {
      unsigned int* pw = (unsigned int*)&Ps[w][lq][0];
#pragma unroll
      for (int mb = 0; mb < 4; ++mb) {
        const unsigned int u0 =
            (unsigned int)f2bf(pv[(mb << 2) + 0]) | ((unsigned int)f2bf(pv[(mb << 2) + 1]) << 16);
        const unsigned int u1 =
            (unsigned int)f2bf(pv[(mb << 2) + 2]) | ((unsigned int)f2bf(pv[(mb << 2) + 3]) << 16);
        pw[(mb << 3) + (g << 1) + 0] = u0;
        pw[(mb << 3) + (g << 1) + 1] = u1;
      }
    }
    // wave-private: only need our own writes visible to our own reads
    asm volatile("s_waitcnt lgkmcnt(0)" ::: "memory");

    // O += P * V  (A = P[q][key], B = V[key][d] via transposed Vs rows)
    {
      const bf16x8 pa0 = *(const bf16x8*)&Ps[w][lq][(g << 3)];
      const bf16x8 pa1 = *(const bf16x8*)&Ps[w][lq][(g << 3) + 32];
      __builtin_amdgcn_s_setprio(1);
#pragma unroll
      for (int nb = 0; nb < 4; ++nb) {
        const bf16x8 v0 = *(const bf16x8*)&Vs[(nb << 4) + lq][(g << 3)];
        const bf16x8 v1 = *(const bf16x8*)&Vs[(nb << 4) + lq][(g << 3) + 32];
        o[nb] = __builtin_amdgcn_mfma_f32_16x16x32_bf16(pa0, v0, o[nb], 0, 0, 0);
        o[nb] = __builtin_amdgcn_mfma_f32_16x16x32_bf16(pa1, v1, o[nb], 0, 0, 0);
      }
      __builtin_amdgcn_s_setprio(0);
    }
    __syncthreads();
  }

  // normalize + write hi/lo: o[nb][r] = O[q=4g+r][d=16nb+lq]
  float li[4];
#pragma unroll
  for (int r = 0; r < 4; ++r)
    li[r] = 1.f / __shfl(lrun, (lane & 48) | ((g << 2) + r), 64);
#pragma unroll
  for (int nb = 0; nb < 4; ++nb)
#pragma unroll
    for (int r = 0; r < 4; ++r) {
      const float val = o[nb][r] * li[r];
      const unsigned short hb = f2bf(val);
      const size_t idx =
          (size_t)(q0 + (w << 4) + (g << 2) + r) * EMB + (nb << 4) + lq;
      Ohb[idx] = hb;
      Olb[idx] = f2bf(val - bf2f(hb));
    }
}

// ---------------------------------------------------------------------------
extern "C" void kernel_launch(void* const* d_in, const int* in_sizes, int n_in,
                              void* d_out, int out_size, void* d_ws, size_t ws_size,
                              hipStream_t stream) {
  const float* x  = (const float*)d_in[0];
  const float* Wk = (const float*)d_in[1];
  const float* Wq = (const float*)d_in[2];
  const float* Wv = (const float*)d_in[3];
  const float* Wu = (const float*)d_in[4];
  const float* klnw = (const float*)d_in[5];
  const float* klnb = (const float*)d_in[6];
  const float* qlnw = (const float*)d_in[7];
  const float* qlnb = (const float*)d_in[8];
  float* out = (float*)d_out;

  char* wsb = (char*)d_ws;
  const size_t MB = 1024 * 1024;
  unsigned short* ah   = (unsigned short*)(wsb + 0 * MB);    // attn out hi (16MB)
  unsigned short* al   = (unsigned short*)(wsb + 16 * MB);   // attn out lo (16MB)
  unsigned short* kb16 = (unsigned short*)(wsb + 32 * MB);
  unsigned short* qb16 = (unsigned short*)(wsb + 48 * MB);
  unsigned short* xh   = (unsigned short*)(wsb + 64 * MB);
  unsigned short* xl   = (unsigned short*)(wsb + 80 * MB);
  unsigned short* vb16 = (unsigned short*)(wsb + 96 * MB);
  unsigned short* wkh  = (unsigned short*)(wsb + 112 * MB);
  unsigned short* wkl  = (unsigned short*)(wsb + 114 * MB);
  unsigned short* wqh  = (unsigned short*)(wsb + 116 * MB);
  unsigned short* wql  = (unsigned short*)(wsb + 118 * MB);
  unsigned short* wvh  = (unsigned short*)(wsb + 120 * MB);
  unsigned short* wvl  = (unsigned short*)(wsb + 122 * MB);
  unsigned short* wuh  = (unsigned short*)(wsb + 124 * MB);
  unsigned short* wul  = (unsigned short*)(wsb + 126 * MB);

  // 1) hi/lo decomposition of x and all weights (xl kept: cheap, layout stable)
  decomp_kernel<<<6144, 256, 0, stream>>>(x, Wk, Wq, Wv, Wu, xh, xl, wkh, wkl,
                                          wqh, wql, wvh, wvl, wuh, wul);

  // 2) QKV projections (2-pass split-bf16 MFMA) + fused per-head LN; v -> bf16^T
  gemm3_qkv_kernel<<<dim3(MROWS / 128, 24), 256, 0, stream>>>(
      xh, wkh, wkl, wqh, wql, wvh, wvl, kb16, qb16, vb16,
      klnw, klnb, qlnw, qlnb);

  // 3) bf16-MFMA causal flash attention -> hi/lo bf16
  attn_kernel<<<dim3(TSEQ / 64, NBATCH * NHEAD), 256, 0, stream>>>(
      qb16, kb16, vb16, ah, al);

  // 4) output projection (2-pass split-bf16 MFMA) -> fp32 out
  gemm3_out_kernel<<<dim3(MROWS / 128, EMB / 128), 256, 0, stream>>>(
      ah, wuh, wul, out);
}

// Round 10
// 349.614 us; speedup vs baseline: 1.4463x; 1.1468x over previous
//
#include <hip/hip_runtime.h>
#include <math.h>

#define EMB 1024
#define TSEQ 2048
#define NBATCH 4
#define NHEAD 16
#define HDIM 64
#define MROWS (NBATCH * TSEQ) /* 8192 */
#define KPAD 72

typedef __attribute__((ext_vector_type(8))) short bf16x8;
typedef __attribute__((ext_vector_type(4))) float f32x4;
typedef __attribute__((ext_vector_type(8))) unsigned short u16x8;
typedef __attribute__((ext_vector_type(4))) unsigned short u16x4;

typedef __attribute__((address_space(1))) const void gas_cv;
typedef __attribute__((address_space(3))) void las_v;

__device__ __forceinline__ void gload_lds16(const void* g, void* l) {
  __builtin_amdgcn_global_load_lds((gas_cv*)g, (las_v*)l, 16, 0, 0);
}

__device__ __forceinline__ unsigned short f2bf(float f) {
  unsigned int x = __float_as_uint(f);
  unsigned int r = x + 0x7fffu + ((x >> 16) & 1u);
  return (unsigned short)(r >> 16);
}
__device__ __forceinline__ float bf2f(unsigned short h) {
  return __uint_as_float((unsigned int)h << 16);
}

// ---------------------------------------------------------------------------
// Decompose fp32 tensors into bf16 hi/lo pairs. 12M elems total, 8 per thread.
// ---------------------------------------------------------------------------
__global__ __launch_bounds__(256) void decomp_kernel(
    const float* __restrict__ x, const float* __restrict__ Wk,
    const float* __restrict__ Wq, const float* __restrict__ Wv,
    const float* __restrict__ Wu,
    unsigned short* __restrict__ xh, unsigned short* __restrict__ xl,
    unsigned short* __restrict__ wkh, unsigned short* __restrict__ wkl,
    unsigned short* __restrict__ wqh, unsigned short* __restrict__ wql,
    unsigned short* __restrict__ wvh, unsigned short* __restrict__ wvl,
    unsigned short* __restrict__ wuh, unsigned short* __restrict__ wul) {
  const int v = blockIdx.x * blockDim.x + threadIdx.x;  // vec8 id
  const float* src;
  unsigned short *dh, *dl;
  size_t off;
  if (v < (1 << 20)) {
    src = x; dh = xh; dl = xl; off = (size_t)v << 3;
  } else {
    const int wv = v - (1 << 20);
    const int ws_ = wv >> 17;
    off = (size_t)(wv & 131071) << 3;
    if (ws_ == 0) { src = Wk; dh = wkh; dl = wkl; }
    else if (ws_ == 1) { src = Wq; dh = wqh; dl = wql; }
    else if (ws_ == 2) { src = Wv; dh = wvh; dl = wvl; }
    else { src = Wu; dh = wuh; dl = wul; }
  }
  const float4 f0 = *(const float4*)(src + off);
  const float4 f1 = *(const float4*)(src + off + 4);
  const float fv[8] = {f0.x, f0.y, f0.z, f0.w, f1.x, f1.y, f1.z, f1.w};
  u16x8 h, l;
#pragma unroll
  for (int i = 0; i < 8; ++i) {
    const unsigned short hb = f2bf(fv[i]);
    h[i] = hb;
    l[i] = f2bf(fv[i] - bf2f(hb));
  }
  *(u16x8*)(dh + off) = h;
  *(u16x8*)(dl + off) = l;
}

// ---------------------------------------------------------------------------
// Split-bf16 2-pass MFMA GEMM core: acc = A*B^T over K=1024 as hi*hi + hi*lo.
// ---------------------------------------------------------------------------
__device__ __forceinline__ void gemm3_core(
    const unsigned short* __restrict__ Ah,
    const unsigned short* __restrict__ Bh, const unsigned short* __restrict__ Bl,
    int bm, int bn, f32x4 acc[4][4]) {
  __shared__ __align__(16) unsigned short As[128][64];
  __shared__ __align__(16) unsigned short Bs[128][64];
  const int tid = threadIdx.x;
  const int lane = tid & 63;
  const int w = tid >> 6;
  const int lq = lane & 15;
  const int g = lane >> 4;
  const int wrO = (w >> 1) << 6;
  const int wcO = (w & 1) << 6;
  const int srow = (w << 5) + (lane >> 3);
  const int scbs = ((lane & 7) ^ (srow & 7)) << 3;  // pre-swizzled src col (elems)
  const int xsw = lq & 7;                           // read-side swizzle

  const size_t aoff0 = (size_t)(bm + srow) * EMB + scbs;
  const size_t boff0 = (size_t)(bn + srow) * EMB + scbs;

  for (int s = 0; s < 32; ++s) {
    const int p = s >> 4;
    const int kt = s & 15;
    const unsigned short* Bsrc = (p == 0) ? Bh : Bl;
    const size_t ko = (size_t)(kt << 6);
    __syncthreads();  // previous compute done before overwrite
#pragma unroll
    for (int u = 0; u < 4; ++u) {
      gload_lds16(Ah + aoff0 + ko + (size_t)(u << 3) * EMB,
                  &As[(w << 5) + (u << 3)][0]);
      gload_lds16(Bsrc + boff0 + ko + (size_t)(u << 3) * EMB,
                  &Bs[(w << 5) + (u << 3)][0]);
    }
    __syncthreads();  // vmcnt drained by compiler before barrier

    bf16x8 af[4][2], bf[4][2];
#pragma unroll
    for (int m = 0; m < 4; ++m)
#pragma unroll
      for (int kk = 0; kk < 2; ++kk) {
        af[m][kk] = *(const bf16x8*)&As[wrO + (m << 4) + lq]
                                      [(((kk << 2) + g) ^ xsw) << 3];
        bf[m][kk] = *(const bf16x8*)&Bs[wcO + (m << 4) + lq]
                                      [(((kk << 2) + g) ^ xsw) << 3];
      }
#pragma unroll
    for (int kk = 0; kk < 2; ++kk)
#pragma unroll
      for (int m = 0; m < 4; ++m)
#pragma unroll
        for (int nb = 0; nb < 4; ++nb)
          acc[m][nb] = __builtin_amdgcn_mfma_f32_16x16x32_bf16(
              af[m][kk], bf[nb][kk], acc[m][nb], 0, 0, 0);
  }
}

// ---------------------------------------------------------------------------
// QKV projections with fused per-head LayerNorm (k,q -> bf16) and transposed
// bf16 v. Grid (64, 24): blockIdx.y>>3 selects k/q/v.
// ---------------------------------------------------------------------------
__global__ __launch_bounds__(256, 2) void gemm3_qkv_kernel(
    const unsigned short* __restrict__ xh,
    const unsigned short* __restrict__ wkh, const unsigned short* __restrict__ wkl,
    const unsigned short* __restrict__ wqh, const unsigned short* __restrict__ wql,
    const unsigned short* __restrict__ wvh, const unsigned short* __restrict__ wvl,
    unsigned short* __restrict__ kb16, unsigned short* __restrict__ qb16,
    unsigned short* __restrict__ vb16,
    const float* __restrict__ klnw, const float* __restrict__ klnb,
    const float* __restrict__ qlnw, const float* __restrict__ qlnb) {
  const int sel = blockIdx.y >> 3;
  const int bm = blockIdx.x << 7;
  const int bn = (blockIdx.y & 7) << 7;
  const unsigned short* Bh = sel == 0 ? wkh : sel == 1 ? wqh : wvh;
  const unsigned short* Bl = sel == 0 ? wkl : sel == 1 ? wql : wvl;

  f32x4 acc[4][4];
#pragma unroll
  for (int m = 0; m < 4; ++m)
#pragma unroll
    for (int nb = 0; nb < 4; ++nb) acc[m][nb] = (f32x4){0.f, 0.f, 0.f, 0.f};

  gemm3_core(xh, Bh, Bl, bm, bn, acc);

  const int lane = threadIdx.x & 63;
  const int w = threadIdx.x >> 6;
  const int lq = lane & 15;
  const int g = lane >> 4;
  const int wrO = (w >> 1) << 6;
  const int wcO = (w & 1) << 6;

  if (sel < 2) {
    // fused per-head LayerNorm: each wave's 64-col span is exactly one head
    unsigned short* C = sel == 0 ? kb16 : qb16;
    const float* lw = sel == 0 ? klnw : qlnw;
    const float* lb = sel == 0 ? klnb : qlnb;
    float wd[4], bd[4];
#pragma unroll
    for (int nb = 0; nb < 4; ++nb) {
      wd[nb] = lw[(nb << 4) + lq];
      bd[nb] = lb[(nb << 4) + lq];
    }
#pragma unroll
    for (int m = 0; m < 4; ++m) {
      const int r0 = bm + wrO + (m << 4) + (g << 2);
#pragma unroll
      for (int j = 0; j < 4; ++j) {
        float s = acc[m][0][j] + acc[m][1][j] + acc[m][2][j] + acc[m][3][j];
        s += __shfl_xor(s, 1, 64); s += __shfl_xor(s, 2, 64);
        s += __shfl_xor(s, 4, 64); s += __shfl_xor(s, 8, 64);
        const float mu = s * (1.f / 64.f);
        float v2 = 0.f;
#pragma unroll
        for (int nb = 0; nb < 4; ++nb) {
          const float d = acc[m][nb][j] - mu;
          v2 = fmaf(d, d, v2);
        }
        v2 += __shfl_xor(v2, 1, 64); v2 += __shfl_xor(v2, 2, 64);
        v2 += __shfl_xor(v2, 4, 64); v2 += __shfl_xor(v2, 8, 64);
        const float inv = rsqrtf(v2 * (1.f / 64.f) + 1e-5f);
#pragma unroll
        for (int nb = 0; nb < 4; ++nb) {
          const float val = (acc[m][nb][j] - mu) * inv * wd[nb] + bd[nb];
          C[(size_t)(r0 + j) * EMB + bn + wcO + (nb << 4) + lq] = f2bf(val);
        }
      }
    }
  } else {
    // v: bf16, transposed per head: vb16[((b*16+h)*64+d)*2048 + t]
#pragma unroll
    for (int m = 0; m < 4; ++m) {
      const int r0 = bm + wrO + (m << 4) + (g << 2);
      const int bb = r0 >> 11;
      const int tl = r0 & 2047;
#pragma unroll
      for (int nb = 0; nb < 4; ++nb) {
        const int n = bn + wcO + (nb << 4) + lq;
        const int hh = n >> 6;
        const int dd = n & 63;
        u16x4 pk;
#pragma unroll
        for (int j = 0; j < 4; ++j) pk[j] = f2bf(acc[m][nb][j]);
        *(u16x4*)(vb16 + ((((size_t)(bb << 4) + hh) << 6) + dd) * TSEQ + tl) = pk;
      }
    }
  }
}

// ---------------------------------------------------------------------------
// Output projection: A = attention out (hi bf16), B = Wu (hi/lo), C fp32.
// ---------------------------------------------------------------------------
__global__ __launch_bounds__(256, 2) void gemm3_out_kernel(
    const unsigned short* __restrict__ ah,
    const unsigned short* __restrict__ wuh, const unsigned short* __restrict__ wul,
    float* __restrict__ C) {
  const int bm = blockIdx.x << 7;
  const int bn = blockIdx.y << 7;
  f32x4 acc[4][4];
#pragma unroll
  for (int m = 0; m < 4; ++m)
#pragma unroll
    for (int nb = 0; nb < 4; ++nb) acc[m][nb] = (f32x4){0.f, 0.f, 0.f, 0.f};

  gemm3_core(ah, wuh, wul, bm, bn, acc);

  const int lane = threadIdx.x & 63;
  const int w = threadIdx.x >> 6;
  const int lq = lane & 15;
  const int g = lane >> 4;
  const int wrO = (w >> 1) << 6;
  const int wcO = (w & 1) << 6;
#pragma unroll
  for (int m = 0; m < 4; ++m) {
    const int r0 = bm + wrO + (m << 4) + (g << 2);
#pragma unroll
    for (int nb = 0; nb < 4; ++nb) {
      const int c = bn + wcO + (nb << 4) + lq;
#pragma unroll
      for (int j = 0; j < 4; ++j) C[(size_t)(r0 + j) * EMB + c] = acc[m][nb][j];
    }
  }
}

// ---------------------------------------------------------------------------
// bf16-MFMA causal flash attention, v4: PAIRED q-tiles per block.
// Block handles q-tiles jA=blockIdx.x and jB=31-jA; kv loop 0..jB; sub-tile A
// active while t<=jA. Work = 33 subtile-units for EVERY block; grid 16x64 =
// 1024 blocks = 4/CU, all resident (27.6 KB LDS). K/V stage + barriers are
// amortized over up to 2x the MFMA work. Softmax: exp2 domain, defer-max
// THR=0, setprio on MFMA clusters. Output: hi bf16 only (lo was dead).
// ---------------------------------------------------------------------------
#define SCL2E 0.1803368801111244f /* 0.125 * log2(e) */

__device__ __forceinline__ void attn_subtile(
    const bf16x8& qf0, const bf16x8& qf1, f32x4 o[4], float& mrun, float& lrun,
    int qg_row, int k0, bool diag,
    const unsigned short (*__restrict__ Ksl)[KPAD],
    const unsigned short (*__restrict__ Vsl)[KPAD],
    unsigned short (*__restrict__ Psl)[KPAD],  // per-wave [16][KPAD]
    int lane, int lq, int g) {
  // S^T = K * Q^T : sacc[mb] rows = key 16mb+4g+r, col = q lq
  f32x4 sacc[4];
#pragma unroll
  for (int mb = 0; mb < 4; ++mb) sacc[mb] = (f32x4){0.f, 0.f, 0.f, 0.f};
  __builtin_amdgcn_s_setprio(1);
#pragma unroll
  for (int mb = 0; mb < 4; ++mb) {
    const bf16x8 ka0 = *(const bf16x8*)&Ksl[(mb << 4) + lq][(g << 3)];
    const bf16x8 ka1 = *(const bf16x8*)&Ksl[(mb << 4) + lq][(g << 3) + 32];
    sacc[mb] = __builtin_amdgcn_mfma_f32_16x16x32_bf16(ka0, qf0, sacc[mb], 0, 0, 0);
    sacc[mb] = __builtin_amdgcn_mfma_f32_16x16x32_bf16(ka1, qf1, sacc[mb], 0, 0, 0);
  }
  __builtin_amdgcn_s_setprio(0);

  // online softmax in exp2 domain (per q = lq; lane holds 16 of 64 keys)
  float pv[16];
  float pm = -3.0e38f;
#pragma unroll
  for (int mb = 0; mb < 4; ++mb)
#pragma unroll
    for (int r = 0; r < 4; ++r) {
      float s = sacc[mb][r] * SCL2E;
      if (diag && (k0 + (mb << 4) + (g << 2) + r) > qg_row) s = -3.0e38f;
      pv[(mb << 2) + r] = s;
      pm = fmaxf(pm, s);
    }
  pm = fmaxf(pm, __shfl_xor(pm, 16, 64));
  pm = fmaxf(pm, __shfl_xor(pm, 32, 64));

  const bool skip = __all(pm <= mrun);  // T13 THR=0: rescale is identity
  const float mnew = skip ? mrun : fmaxf(mrun, pm);
  float ls = 0.f;
#pragma unroll
  for (int i = 0; i < 16; ++i) {
    const float p = exp2f(pv[i] - mnew);
    pv[i] = p;
    ls += p;
  }
  ls += __shfl_xor(ls, 16, 64);
  ls += __shfl_xor(ls, 32, 64);
  if (skip) {
    lrun += ls;
  } else {
    const float corr = exp2f(mrun - mnew);  // exp2(-inf)=0 on first tile
    mrun = mnew;
    lrun = lrun * corr + ls;
    float corr4[4];
#pragma unroll
    for (int r = 0; r < 4; ++r)
      corr4[r] = __shfl(corr, (lane & 48) | ((g << 2) + r), 64);
#pragma unroll
    for (int nb = 0; nb < 4; ++nb)
#pragma unroll
      for (int r = 0; r < 4; ++r) o[nb][r] *= corr4[r];
  }

  // pack P (bf16) into per-wave LDS: Psl[q=lq][key]
  {
    unsigned int* pw = (unsigned int*)&Psl[lq][0];
#pragma unroll
    for (int mb = 0; mb < 4; ++mb) {
      const unsigned int u0 =
          (unsigned int)f2bf(pv[(mb << 2) + 0]) | ((unsigned int)f2bf(pv[(mb << 2) + 1]) << 16);
      const unsigned int u1 =
          (unsigned int)f2bf(pv[(mb << 2) + 2]) | ((unsigned int)f2bf(pv[(mb << 2) + 3]) << 16);
      pw[(mb << 3) + (g << 1) + 0] = u0;
      pw[(mb << 3) + (g << 1) + 1] = u1;
    }
  }
  // wave-private: only need our own writes visible to our own reads
  asm volatile("s_waitcnt lgkmcnt(0)" ::: "memory");

  // O += P * V  (A = P[q][key], B = V[key][d] via transposed Vs rows)
  {
    const bf16x8 pa0 = *(const bf16x8*)&Psl[lq][(g << 3)];
    const bf16x8 pa1 = *(const bf16x8*)&Psl[lq][(g << 3) + 32];
    __builtin_amdgcn_s_setprio(1);
#pragma unroll
    for (int nb = 0; nb < 4; ++nb) {
      const bf16x8 v0 = *(const bf16x8*)&Vsl[(nb << 4) + lq][(g << 3)];
      const bf16x8 v1 = *(const bf16x8*)&Vsl[(nb << 4) + lq][(g << 3) + 32];
      o[nb] = __builtin_amdgcn_mfma_f32_16x16x32_bf16(pa0, v0, o[nb], 0, 0, 0);
      o[nb] = __builtin_amdgcn_mfma_f32_16x16x32_bf16(pa1, v1, o[nb], 0, 0, 0);
    }
    __builtin_amdgcn_s_setprio(0);
  }
}

__global__ __launch_bounds__(256, 4) void attn_kernel(
    const unsigned short* __restrict__ Qg, const unsigned short* __restrict__ Kg,
    const unsigned short* __restrict__ Vt, unsigned short* __restrict__ Oh) {
  __shared__ __align__(16) unsigned short Ks[64][KPAD];
  __shared__ __align__(16) unsigned short Vs[64][KPAD];
  __shared__ __align__(16) unsigned short Ps[4][16][KPAD];
  const int tid = threadIdx.x;
  const int lane = tid & 63;
  const int w = tid >> 6;
  const int lq = lane & 15;
  const int g = lane >> 4;
  const int jA = blockIdx.x;                 // 0..15
  const int jB = (TSEQ / 64 - 1) - jA;       // 31..16
  const int bh = blockIdx.y;
  const int bb = bh >> 4;
  const int hh = bh & 15;
  const int q0A = jA << 6;
  const int q0B = jB << 6;
  const unsigned short* Qb = Qg + ((size_t)bb * TSEQ) * EMB + hh * HDIM;
  const unsigned short* Kb = Kg + ((size_t)bb * TSEQ) * EMB + hh * HDIM;
  const unsigned short* Vb = Vt + (size_t)bh * HDIM * TSEQ;
  unsigned short* Ohb = Oh + ((size_t)bb * TSEQ) * EMB + hh * HDIM;

  bf16x8 qfA0, qfA1, qfB0, qfB1;
  {
    const unsigned short* qpA = Qb + (size_t)(q0A + (w << 4) + lq) * EMB + (g << 3);
    qfA0 = *(const bf16x8*)(qpA);
    qfA1 = *(const bf16x8*)(qpA + 32);
    const unsigned short* qpB = Qb + (size_t)(q0B + (w << 4) + lq) * EMB + (g << 3);
    qfB0 = *(const bf16x8*)(qpB);
    qfB1 = *(const bf16x8*)(qpB + 32);
  }

  f32x4 oA[4], oB[4];
#pragma unroll
  for (int nb = 0; nb < 4; ++nb) {
    oA[nb] = (f32x4){0.f, 0.f, 0.f, 0.f};
    oB[nb] = (f32x4){0.f, 0.f, 0.f, 0.f};
  }
  float mA = -3.0e38f, lA = 0.f, mB = -3.0e38f, lB = 0.f;
  const int qrowA = q0A + (w << 4) + lq;
  const int qrowB = q0B + (w << 4) + lq;

  const int skey = tid >> 2;            // staging row 0..63
  const int schunk = (tid & 3) << 4;    // staging col base (16 elems)

  for (int t = 0; t <= jB; ++t) {
    const int k0 = t << 6;
    // stage K (rows=key, cols=d) and V (rows=d, cols=key; Vt pre-transposed)
    {
      const unsigned short* kp = Kb + (size_t)(k0 + skey) * EMB + schunk;
      *(bf16x8*)&Ks[skey][schunk] = *(const bf16x8*)kp;
      *(bf16x8*)&Ks[skey][schunk + 8] = *(const bf16x8*)(kp + 8);
      const unsigned short* vp = Vb + (size_t)skey * TSEQ + k0 + schunk;
      *(bf16x8*)&Vs[skey][schunk] = *(const bf16x8*)vp;
      *(bf16x8*)&Vs[skey][schunk + 8] = *(const bf16x8*)(vp + 8);
    }
    __syncthreads();

    // sub-tile B always active (t <= jB by loop bound)
    attn_subtile(qfB0, qfB1, oB, mB, lB, qrowB, k0, t == jB,
                 Ks, Vs, Ps[w], lane, lq, g);
    // sub-tile A active while t <= jA
    if (t <= jA)
      attn_subtile(qfA0, qfA1, oA, mA, lA, qrowA, k0, t == jA,
                   Ks, Vs, Ps[w], lane, lq, g);
    __syncthreads();
  }

  // normalize + write (hi bf16 only): o[nb][r] = O[q=4g+r][d=16nb+lq]
  float liA[4], liB[4];
#pragma unroll
  for (int r = 0; r < 4; ++r) {
    liA[r] = 1.f / __shfl(lA, (lane & 48) | ((g << 2) + r), 64);
    liB[r] = 1.f / __shfl(lB, (lane & 48) | ((g << 2) + r), 64);
  }
#pragma unroll
  for (int nb = 0; nb < 4; ++nb)
#pragma unroll
    for (int r = 0; r < 4; ++r) {
      const int rr = (w << 4) + (g << 2) + r;
      Ohb[(size_t)(q0A + rr) * EMB + (nb << 4) + lq] = f2bf(oA[nb][r] * liA[r]);
      Ohb[(size_t)(q0B + rr) * EMB + (nb << 4) + lq] = f2bf(oB[nb][r] * liB[r]);
    }
}

// ---------------------------------------------------------------------------
extern "C" void kernel_launch(void* const* d_in, const int* in_sizes, int n_in,
                              void* d_out, int out_size, void* d_ws, size_t ws_size,
                              hipStream_t stream) {
  const float* x  = (const float*)d_in[0];
  const float* Wk = (const float*)d_in[1];
  const float* Wq = (const float*)d_in[2];
  const float* Wv = (const float*)d_in[3];
  const float* Wu = (const float*)d_in[4];
  const float* klnw = (const float*)d_in[5];
  const float* klnb = (const float*)d_in[6];
  const float* qlnw = (const float*)d_in[7];
  const float* qlnb = (const float*)d_in[8];
  float* out = (float*)d_out;

  char* wsb = (char*)d_ws;
  const size_t MB = 1024 * 1024;
  unsigned short* ah   = (unsigned short*)(wsb + 0 * MB);    // attn out hi (16MB)
  unsigned short* kb16 = (unsigned short*)(wsb + 32 * MB);
  unsigned short* qb16 = (unsigned short*)(wsb + 48 * MB);
  unsigned short* xh   = (unsigned short*)(wsb + 64 * MB);
  unsigned short* xl   = (unsigned short*)(wsb + 80 * MB);
  unsigned short* vb16 = (unsigned short*)(wsb + 96 * MB);
  unsigned short* wkh  = (unsigned short*)(wsb + 112 * MB);
  unsigned short* wkl  = (unsigned short*)(wsb + 114 * MB);
  unsigned short* wqh  = (unsigned short*)(wsb + 116 * MB);
  unsigned short* wql  = (unsigned short*)(wsb + 118 * MB);
  unsigned short* wvh  = (unsigned short*)(wsb + 120 * MB);
  unsigned short* wvl  = (unsigned short*)(wsb + 122 * MB);
  unsigned short* wuh  = (unsigned short*)(wsb + 124 * MB);
  unsigned short* wul  = (unsigned short*)(wsb + 126 * MB);

  // 1) hi/lo decomposition of x and all weights
  decomp_kernel<<<6144, 256, 0, stream>>>(x, Wk, Wq, Wv, Wu, xh, xl, wkh, wkl,
                                          wqh, wql, wvh, wvl, wuh, wul);

  // 2) QKV projections (2-pass split-bf16 MFMA) + fused per-head LN; v -> bf16^T
  gemm3_qkv_kernel<<<dim3(MROWS / 128, 24), 256, 0, stream>>>(
      xh, wkh, wkl, wqh, wql, wvh, wvl, kb16, qb16, vb16,
      klnw, klnb, qlnw, qlnb);

  // 3) bf16-MFMA causal flash attention (paired q-tiles) -> hi bf16
  attn_kernel<<<dim3(TSEQ / 128, NBATCH * NHEAD), 256, 0, stream>>>(
      qb16, kb16, vb16, ah);

  // 4) output projection (2-pass split-bf16 MFMA) -> fp32 out
  gemm3_out_kernel<<<dim3(MROWS / 128, EMB / 128), 256, 0, stream>>>(
      ah, wuh, wul, out);
}